// Round 2
// baseline (3534.000 us; speedup 1.0000x reference)
//
#include <hip/hip_runtime.h>

// Problem constants
#define BATCH   64
#define SEQT    512
#define NIN     512
#define NH      1024
#define NG      4096   // 4*NH

typedef __attribute__((ext_vector_type(8))) short short8;
typedef __attribute__((ext_vector_type(4))) float floatx4;

__device__ __forceinline__ float bf2f(unsigned short u) {
    union { float f; unsigned i; } v; v.i = ((unsigned)u) << 16; return v.f;
}
__device__ __forceinline__ unsigned short f2bf(float f) {
    union { float f; unsigned i; } v; v.f = f;
    unsigned x = v.i;
    unsigned r = (x + 0x7fffu + ((x >> 16) & 1u)) >> 16;  // RNE
    return (unsigned short)r;
}
__device__ __forceinline__ float sigm(float x) { return 1.0f / (1.0f + expf(-x)); }

// ---------------- prep kernels ----------------
__global__ void cvt_bf16(const float* __restrict__ src, unsigned short* __restrict__ dst, long n) {
    long i = (long)blockIdx.x * blockDim.x + threadIdx.x;
    long stride = (long)gridDim.x * blockDim.x;
    for (; i < n; i += stride) dst[i] = f2bf(src[i]);
}

// Rearrange W_hh (4096x1024 fp32) into per-rowgroup bf16 layout with the
// LDS bank-conflict XOR swizzle BAKED IN:
//   dst[rg][row][cs] = W[(g*1024 + rg*16 + nl)][cs ^ ((row&7)<<3)]
// where row = g*16 + nl  (g = gate 0..3, nl = hidden-in-block 0..15).
// Consumer reads W[row][c] at LDS col c ^ ((row&7)<<3) (XOR involution).
__global__ void prep_whh(const float* __restrict__ W, unsigned short* __restrict__ dst) {
    long i = (long)blockIdx.x * blockDim.x + threadIdx.x;
    if (i >= (long)NG * NH) return;
    int cs  = (int)(i & (NH - 1));
    int row = (int)(i >> 10) & 63;
    int rg  = (int)(i >> 16);            // 0..63
    int c   = cs ^ ((row & 7) << 3);
    int g = row >> 4, nl = row & 15;
    long src = ((long)(g * NH + rg * 16 + nl) << 10) + c;
    dst[i] = f2bf(W[src]);
}

// ---------------- precompute GEMM: G = x @ W_ih^T + b_ih + b_hh ----------------
__global__ __launch_bounds__(256) void gemm_ih(const unsigned short* __restrict__ A,
                                               const unsigned short* __restrict__ Wb,
                                               const float* __restrict__ b_ih,
                                               const float* __restrict__ b_hh,
                                               unsigned short* __restrict__ G) {
    __shared__ __align__(16) unsigned short a_lds[128][56];
    __shared__ __align__(16) unsigned short b_lds[128][56];
    const int tid  = threadIdx.x;
    const int lane = tid & 63;
    const int w    = tid >> 6;
    const int wm   = w >> 1, wn = w & 1;
    const int bm   = blockIdx.x, bn = blockIdx.y;

    floatx4 acc[4][4] = {};

    const int row = tid >> 1, seg = tid & 1;
    const unsigned short* gA = A  + ((size_t)(bm * 128 + row)) * NIN + seg * 16;
    const unsigned short* gB = Wb + ((size_t)(bn * 128 + row)) * NIN + seg * 16;

    for (int kt = 0; kt < 16; ++kt) {
        __syncthreads();
        *(uint4*)&a_lds[row][seg * 16]     = *(const uint4*)(gA + kt * 32);
        *(uint4*)&a_lds[row][seg * 16 + 8] = *(const uint4*)(gA + kt * 32 + 8);
        *(uint4*)&b_lds[row][seg * 16]     = *(const uint4*)(gB + kt * 32);
        *(uint4*)&b_lds[row][seg * 16 + 8] = *(const uint4*)(gB + kt * 32 + 8);
        __syncthreads();
        short8 af[4], bf[4];
#pragma unroll
        for (int mt = 0; mt < 4; ++mt)
            af[mt] = *(const short8*)&a_lds[wm * 64 + mt * 16 + (lane & 15)][(lane >> 4) * 8];
#pragma unroll
        for (int nt = 0; nt < 4; ++nt)
            bf[nt] = *(const short8*)&b_lds[wn * 64 + nt * 16 + (lane & 15)][(lane >> 4) * 8];
#pragma unroll
        for (int mt = 0; mt < 4; ++mt)
#pragma unroll
            for (int nt = 0; nt < 4; ++nt)
                acc[mt][nt] = __builtin_amdgcn_mfma_f32_16x16x32_bf16(af[mt], bf[nt], acc[mt][nt], 0, 0, 0);
    }
#pragma unroll
    for (int nt = 0; nt < 4; ++nt) {
        int n = bn * 128 + wn * 64 + nt * 16 + (lane & 15);
        float bias = b_ih[n] + b_hh[n];
#pragma unroll
        for (int mt = 0; mt < 4; ++mt) {
#pragma unroll
            for (int r = 0; r < 4; ++r) {
                int m = bm * 128 + wm * 64 + mt * 16 + (lane >> 4) * 4 + r;  // token
                int b = m >> 9, t = m & 511;
                size_t gi = ((size_t)(t * 64 + b)) * NG + n;
                G[gi] = f2bf(acc[mt][nt][r] + bias);
            }
        }
    }
}

// ---------------- persistent sequential kernel ----------------
// 2-D decomposition: block (bg, rg) with bg = blockIdx.x&3 (16 batches),
// rg = blockIdx.x>>2 (16 hidden units = 64 gate rows of W_hh).
//
// ROUND-2 CHANGE: arrival-ordered chunked consumption, fence-free.
// Each wave's K-chunk c (32 h-units) depends on exactly 2 producers
// (rg = 2c, 2c+1). Instead of {wait for all 64 flags -> buffer_inv ->
// read 32KB -> GEMM}, each wave walks its 8 chunks: poll the 2 flags for
// that chunk, then load its 16B fragment via AGENT-SCOPE RELAXED ATOMIC
// loads (coherent at LLC -> no acquire fence / buffer_inv needed), then
// 4 MFMAs. Early chunks' loads+MFMAs overlap the stragglers' publish
// latency; only the slowest chunk's tail stays on the critical path.
// Ordering: h-loads are control-dependent on the poll branch (HW order),
// atomics are never speculated by the compiler, plus an explicit compiler
// memory barrier. Release side unchanged (proven): scoped 8B stores ->
// __syncthreads (vmcnt drain) -> scoped flag store.
__global__ __launch_bounds__(256, 1) void seq_kernel(const unsigned short* __restrict__ Wp,
                                                     const unsigned short* __restrict__ G,
                                                     unsigned short* __restrict__ hread,
                                                     unsigned* __restrict__ flags,
                                                     float* __restrict__ out) {
    const int tid  = threadIdx.x;
    const int lane = tid & 63;
    const int w    = tid >> 6;
    const int bid  = blockIdx.x;
    const int bg   = bid & 3;        // batch group (16 batches)
    const int rg   = bid >> 2;       // row group (16 hidden, 64 gate rows)

    // W slice 64 rows x 1024, swizzle baked in global layout -> linear copy.
    __shared__ __align__(16) unsigned short w_lds[64 * 1024];
    // cross-wave K-split partials: [wave][m=batch16][n=64] f32, padded to 68
    __shared__ float part[4][16][68];

    {
        const unsigned short* src = Wp + (size_t)rg * 65536;
#pragma unroll 4
        for (int u = 0; u < 32; ++u)
            *(uint4*)&w_lds[u * 2048 + tid * 8] = *(const uint4*)(src + u * 2048 + tid * 8);
    }
    __syncthreads();

    const int cb = tid >> 4;         // batch within group 0..15
    const int nl = tid & 15;         // hidden within block 0..15
    const int b  = bg * 16 + cb;     // global batch
    const int u  = rg * 16 + nl;     // global hidden unit

    float h0 = 0.f, h1 = 0.f, h2 = 0.f, h3 = 0.f;
    float c0 = 0.f, c1 = 0.f, c2 = 0.f, c3 = 0.f;
    float c_read = 0.f;

    const unsigned short* Gp = G + (size_t)b * NG + u;
    float* out_h = out + (size_t)b * SEQT * NH + u;

    // publish: h stored in MFMA-fragment order per group:
    //   idx = (kchunk*64 + lane)*8 + j ; kchunk = u>>5, lane = (kin>>3)*16 + cb,
    //   j = kin&7, kin = u&31 = (rg&1)*16 + nl.
    const size_t pub_idx = ((size_t)((rg >> 1) * 64 + ((rg & 1) * 2 + (nl >> 3)) * 16 + cb)) * 8 + (nl & 7);
    const int swz   = (lane & 7) << 3; // row&7 == lane&7 for all nt tiles
    const int brow0 = lane & 15;
    const int kofs  = (lane >> 4) * 8;
    const unsigned* fgrp = flags + bg * 64;

    for (int t = 0; t < SEQT; ++t) {
        // prefetch this thread's 4 input-projection gates (HBM) before any wait
        const unsigned short* Gt = Gp + (size_t)t * 64 * NG;
        unsigned short gi_u = Gt[0], gf_u = Gt[1024], gg_u = Gt[2048], go_u = Gt[3072];

        // GEMM: gates[16 x 64] = h[16 x 1024] @ Wslice^T ; wave w owns K-slice
        // [w*256, (w+1)*256), consumed as 8 chunks with per-chunk flag polls.
        const size_t abase = (size_t)(t & 1) * 65536 + (size_t)bg * 16384;
        floatx4 acc[4] = {};
#pragma unroll
        for (int kk = 0; kk < 8; ++kk) {
            const int c = w * 8 + kk;
            // W fragments first (LDS; independent of the exchange)
            short8 bfr[4];
            const int cbase = (c * 32 + kofs) ^ swz;
#pragma unroll
            for (int nt = 0; nt < 4; ++nt)
                bfr[nt] = *(const short8*)&w_lds[(nt * 16 + brow0) * 1024 + cbase];
            if (t > 0) {
                // chunk c needs producers rg = 2c and 2c+1 at step >= t
                const unsigned* fp = fgrp + 2 * c + (lane & 1);
                while (!__all((int)(__hip_atomic_load(fp, __ATOMIC_RELAXED, __HIP_MEMORY_SCOPE_AGENT) >= (unsigned)t)))
                    __builtin_amdgcn_s_sleep(1);
                asm volatile("" ::: "memory");
            }
            const unsigned long long* ap =
                (const unsigned long long*)(hread + abase + ((size_t)(c * 64 + lane)) * 8);
            union { unsigned long long q[2]; short8 v; } au;
            au.q[0] = __hip_atomic_load(ap,     __ATOMIC_RELAXED, __HIP_MEMORY_SCOPE_AGENT);
            au.q[1] = __hip_atomic_load(ap + 1, __ATOMIC_RELAXED, __HIP_MEMORY_SCOPE_AGENT);
#pragma unroll
            for (int nt = 0; nt < 4; ++nt)
                acc[nt] = __builtin_amdgcn_mfma_f32_16x16x32_bf16(au.v, bfr[nt], acc[nt], 0, 0, 0);
        }
        // D[m][n]: m = (lane>>4)*4 + r (batch), n = nt*16 + (lane&15) (gate row)
#pragma unroll
        for (int nt = 0; nt < 4; ++nt)
#pragma unroll
            for (int r = 0; r < 4; ++r)
                part[w][(lane >> 4) * 4 + r][nt * 16 + (lane & 15)] = acc[nt][r];
        __syncthreads();

        // reduce 4 wave-partials + LSTM cell for (b, u)
        float gi = (part[0][cb][nl]      + part[1][cb][nl])      + (part[2][cb][nl]      + part[3][cb][nl]);
        float gf = (part[0][cb][16 + nl] + part[1][cb][16 + nl]) + (part[2][cb][16 + nl] + part[3][cb][16 + nl]);
        float gg = (part[0][cb][32 + nl] + part[1][cb][32 + nl]) + (part[2][cb][32 + nl] + part[3][cb][32 + nl]);
        float go = (part[0][cb][48 + nl] + part[1][cb][48 + nl]) + (part[2][cb][48 + nl] + part[3][cb][48 + nl]);
        gi += bf2f(gi_u); gf += bf2f(gf_u); gg += bf2f(gg_u); go += bf2f(go_u);

        float c = sigm(gf) * c_read + sigm(gi) * tanhf(gg);
        float h = sigm(go) * tanhf(c);

        out_h[(size_t)t * NH] = h;
        if (t == SEQT - 1) {
            float* o2 = out + (size_t)BATCH * SEQT * NH + (size_t)b * 2 * NH;
            o2[u] = h;
            o2[NH + u] = c;
        }

        // shift ring, compute interpolated read state for step t+1
        h3 = h2; h2 = h1; h1 = h0; h0 = h;
        c3 = c2; c2 = c1; c1 = c0; c0 = c;
        float hr = 0.3125f * h0 + 0.9375f * h1 - 0.3125f * h2 + 0.0625f * h3;
        c_read   = 0.3125f * c0 + 0.9375f * c1 - 0.3125f * c2 + 0.0625f * c3;

        // publish hr (bf16): pack 4 adjacent shorts via 2 shuffles -> one 8B
        // agent-scope write-through store per 4 threads
        {
            unsigned v  = (unsigned)f2bf(hr);
            unsigned p0 = v | (__shfl_xor(v, 1) << 16);     // valid at even nl
            unsigned p2 = __shfl_xor(p0, 2);                // partner pair
            if ((nl & 3) == 0) {
                unsigned long long q = (unsigned long long)p0 | ((unsigned long long)p2 << 32);
                unsigned long long* dst = (unsigned long long*)(hread
                    + (size_t)((t + 1) & 1) * 65536 + (size_t)bg * 16384 + pub_idx);
                __hip_atomic_store(dst, q, __ATOMIC_RELAXED, __HIP_MEMORY_SCOPE_AGENT);
            }
        }

        __syncthreads();  // drains vmcnt(0): all scoped stores of this block at LLC
        if (tid == 0)
            __hip_atomic_store(&flags[bg * 64 + rg], (unsigned)(t + 1), __ATOMIC_RELAXED, __HIP_MEMORY_SCOPE_AGENT);
    }
}

// ---------------- host ----------------
extern "C" void kernel_launch(void* const* d_in, const int* in_sizes, int n_in,
                              void* d_out, int out_size, void* d_ws, size_t ws_size,
                              hipStream_t stream) {
    const float* x    = (const float*)d_in[0];
    const float* Wih  = (const float*)d_in[1];
    const float* Whh  = (const float*)d_in[2];
    const float* bih  = (const float*)d_in[3];
    const float* bhh  = (const float*)d_in[4];
    float* outp = (float*)d_out;

    char* ws = (char*)d_ws;
    unsigned short* xb    = (unsigned short*)(ws);                 // 33,554,432 B
    unsigned short* wihb  = (unsigned short*)(ws + 33554432);      //  4,194,304 B
    unsigned short* whhb  = (unsigned short*)(ws + 37748736);      //  8,388,608 B
    unsigned short* G     = (unsigned short*)(ws + 46137344);      // 268,435,456 B
    unsigned short* hread = (unsigned short*)(ws + 314572800);     //    262,144 B
    unsigned*       flags = (unsigned*)(ws + 314834944);           //      1,024 B

    // zero hread (step-0 state) and flags; visible to seq_kernel via dispatch boundary
    hipMemsetAsync(hread, 0, 262144 + 1024, stream);

    cvt_bf16<<<4096, 256, 0, stream>>>(x, xb, (long)BATCH * SEQT * NIN);
    cvt_bf16<<<2048, 256, 0, stream>>>(Wih, wihb, (long)NG * NIN);
    prep_whh<<<16384, 256, 0, stream>>>(Whh, whhb);
    gemm_ih<<<dim3(256, 32), 256, 0, stream>>>(xb, wihb, bih, bhh, G);

    void* args[] = { (void*)&whhb, (void*)&G, (void*)&hread, (void*)&flags, (void*)&outp };
    hipLaunchCooperativeKernel((void*)seq_kernel, dim3(256), dim3(256), args, 0, stream);
}

// Round 3
// 2332.399 us; speedup vs baseline: 1.5152x; 1.5152x over previous
//
#include <hip/hip_runtime.h>

// Problem constants
#define BATCH   64
#define SEQT    512
#define NIN     512
#define NH      1024
#define NG      4096   // 4*NH

typedef __attribute__((ext_vector_type(8))) short short8;
typedef __attribute__((ext_vector_type(4))) float floatx4;

__device__ __forceinline__ float bf2f(unsigned short u) {
    union { float f; unsigned i; } v; v.i = ((unsigned)u) << 16; return v.f;
}
__device__ __forceinline__ unsigned short f2bf(float f) {
    union { float f; unsigned i; } v; v.f = f;
    unsigned x = v.i;
    unsigned r = (x + 0x7fffu + ((x >> 16) & 1u)) >> 16;  // RNE
    return (unsigned short)r;
}
// fast activations: v_exp_f32 + v_rcp_f32, no libm slow paths.
// sigm: exact at extremes (exp->inf => 0; exp->0 => 1). tanh = 1 - 2/(1+e^{2x}).
__device__ __forceinline__ float fsigm(float x) {
    return __builtin_amdgcn_rcpf(1.0f + __expf(-x));
}
__device__ __forceinline__ float ftanh(float x) {
    return 1.0f - 2.0f * __builtin_amdgcn_rcpf(1.0f + __expf(2.0f * x));
}

// ---------------- prep kernels ----------------
__global__ void cvt_bf16(const float* __restrict__ src, unsigned short* __restrict__ dst, long n) {
    long i = (long)blockIdx.x * blockDim.x + threadIdx.x;
    long stride = (long)gridDim.x * blockDim.x;
    for (; i < n; i += stride) dst[i] = f2bf(src[i]);
}

// Rearrange W_hh (4096x1024 fp32) into per-rowgroup bf16 layout with the
// LDS bank-conflict XOR swizzle BAKED IN:
//   dst[rg][row][cs] = W[(g*1024 + rg*16 + nl)][cs ^ ((row&7)<<3)]
// where row = g*16 + nl  (g = gate 0..3, nl = hidden-in-block 0..15).
// Consumer reads W[row][c] at LDS col c ^ ((row&7)<<3) (XOR involution).
__global__ void prep_whh(const float* __restrict__ W, unsigned short* __restrict__ dst) {
    long i = (long)blockIdx.x * blockDim.x + threadIdx.x;
    if (i >= (long)NG * NH) return;
    int cs  = (int)(i & (NH - 1));
    int row = (int)(i >> 10) & 63;
    int rg  = (int)(i >> 16);            // 0..63
    int c   = cs ^ ((row & 7) << 3);
    int g = row >> 4, nl = row & 15;
    long src = ((long)(g * NH + rg * 16 + nl) << 10) + c;
    dst[i] = f2bf(W[src]);
}

// ---------------- precompute GEMM: G = x @ W_ih^T + b_ih + b_hh ----------------
__global__ __launch_bounds__(256) void gemm_ih(const unsigned short* __restrict__ A,
                                               const unsigned short* __restrict__ Wb,
                                               const float* __restrict__ b_ih,
                                               const float* __restrict__ b_hh,
                                               unsigned short* __restrict__ G) {
    __shared__ __align__(16) unsigned short a_lds[128][56];
    __shared__ __align__(16) unsigned short b_lds[128][56];
    const int tid  = threadIdx.x;
    const int lane = tid & 63;
    const int w    = tid >> 6;
    const int wm   = w >> 1, wn = w & 1;
    const int bm   = blockIdx.x, bn = blockIdx.y;

    floatx4 acc[4][4] = {};

    const int row = tid >> 1, seg = tid & 1;
    const unsigned short* gA = A  + ((size_t)(bm * 128 + row)) * NIN + seg * 16;
    const unsigned short* gB = Wb + ((size_t)(bn * 128 + row)) * NIN + seg * 16;

    for (int kt = 0; kt < 16; ++kt) {
        __syncthreads();
        *(uint4*)&a_lds[row][seg * 16]     = *(const uint4*)(gA + kt * 32);
        *(uint4*)&a_lds[row][seg * 16 + 8] = *(const uint4*)(gA + kt * 32 + 8);
        *(uint4*)&b_lds[row][seg * 16]     = *(const uint4*)(gB + kt * 32);
        *(uint4*)&b_lds[row][seg * 16 + 8] = *(const uint4*)(gB + kt * 32 + 8);
        __syncthreads();
        short8 af[4], bf[4];
#pragma unroll
        for (int mt = 0; mt < 4; ++mt)
            af[mt] = *(const short8*)&a_lds[wm * 64 + mt * 16 + (lane & 15)][(lane >> 4) * 8];
#pragma unroll
        for (int nt = 0; nt < 4; ++nt)
            bf[nt] = *(const short8*)&b_lds[wn * 64 + nt * 16 + (lane & 15)][(lane >> 4) * 8];
#pragma unroll
        for (int mt = 0; mt < 4; ++mt)
#pragma unroll
            for (int nt = 0; nt < 4; ++nt)
                acc[mt][nt] = __builtin_amdgcn_mfma_f32_16x16x32_bf16(af[mt], bf[nt], acc[mt][nt], 0, 0, 0);
    }
#pragma unroll
    for (int nt = 0; nt < 4; ++nt) {
        int n = bn * 128 + wn * 64 + nt * 16 + (lane & 15);
        float bias = b_ih[n] + b_hh[n];
#pragma unroll
        for (int mt = 0; mt < 4; ++mt) {
#pragma unroll
            for (int r = 0; r < 4; ++r) {
                int m = bm * 128 + wm * 64 + mt * 16 + (lane >> 4) * 4 + r;  // token
                int b = m >> 9, t = m & 511;
                size_t gi = ((size_t)(t * 64 + b)) * NG + n;
                G[gi] = f2bf(acc[mt][nt][r] + bias);
            }
        }
    }
}

// ---------------- persistent sequential kernel ----------------
// 2-D decomposition: block (bg, rg) with bg = blockIdx.x&3 (16 batches),
// rg = blockIdx.x>>2 (16 hidden units = 64 gate rows of W_hh).
//
// ROUND-3: round-1 bulk-load structure, with:
//  - per-wave wait on ONLY its 16 producers (wave w consumes chunks 8w..8w+7
//    produced by rg 16w..16w+15; union over waves = all 64, so the ping-pong
//    overwrite safety proof is unchanged: any wave publishes step t+1 only
//    after part-sync joins all waves, i.e. after all 64 flags >= t were seen).
//  - NO acquire fence: h is read via relaxed AGENT-scope atomic loads
//    (LLC-coherent; mechanism proven correct in round 2), bulk-issued as
//    16 parallel 8B loads to keep memory-level parallelism (round-2 lesson:
//    never serialize poll->load chains).
//  - fast activations (v_exp_f32 + v_rcp_f32) — 5 serial transcendentals sit
//    on the critical path each step.
//  - out_h HBM store moved AFTER the flag store: its write-ack no longer
//    sits inside the drain; it completes during the next step.
// Release side unchanged (proven): scoped 8B stores -> __syncthreads (vmcnt
// drain) -> scoped flag store.
__global__ __launch_bounds__(256, 1) void seq_kernel(const unsigned short* __restrict__ Wp,
                                                     const unsigned short* __restrict__ G,
                                                     unsigned short* __restrict__ hread,
                                                     unsigned* __restrict__ flags,
                                                     float* __restrict__ out) {
    const int tid  = threadIdx.x;
    const int lane = tid & 63;
    const int w    = tid >> 6;
    const int bid  = blockIdx.x;
    const int bg   = bid & 3;        // batch group (16 batches)
    const int rg   = bid >> 2;       // row group (16 hidden, 64 gate rows)

    // W slice 64 rows x 1024, swizzle baked in global layout -> linear copy.
    __shared__ __align__(16) unsigned short w_lds[64 * 1024];
    // cross-wave K-split partials: [wave][m=batch16][n=64] f32, padded to 68
    __shared__ float part[4][16][68];

    {
        const unsigned short* src = Wp + (size_t)rg * 65536;
#pragma unroll 4
        for (int u = 0; u < 32; ++u)
            *(uint4*)&w_lds[u * 2048 + tid * 8] = *(const uint4*)(src + u * 2048 + tid * 8);
    }
    __syncthreads();

    const int cb = tid >> 4;         // batch within group 0..15
    const int nl = tid & 15;         // hidden within block 0..15
    const int b  = bg * 16 + cb;     // global batch
    const int u  = rg * 16 + nl;     // global hidden unit

    float h0 = 0.f, h1 = 0.f, h2 = 0.f, h3 = 0.f;
    float c0 = 0.f, c1 = 0.f, c2 = 0.f, c3 = 0.f;
    float c_read = 0.f;

    const unsigned short* Gp = G + (size_t)b * NG + u;
    float* out_h = out + (size_t)b * SEQT * NH + u;

    // publish: h stored in MFMA-fragment order per group:
    //   idx = (kchunk*64 + lane)*8 + j ; kchunk = u>>5, lane = (kin>>3)*16 + cb,
    //   j = kin&7, kin = u&31 = (rg&1)*16 + nl.
    const size_t pub_idx = ((size_t)((rg >> 1) * 64 + ((rg & 1) * 2 + (nl >> 3)) * 16 + cb)) * 8 + (nl & 7);
    const int swz   = (lane & 7) << 3; // row&7 == lane&7 for all nt tiles
    const int brow0 = lane & 15;
    const int kofs  = (lane >> 4) * 8;
    // wave w's producers: flags[bg*64 + 16w .. 16w+15]
    const unsigned* fwave = flags + bg * 64 + w * 16 + (lane & 15);

    for (int t = 0; t < SEQT; ++t) {
        // prefetch this thread's 4 input-projection gates (HBM) before any wait
        const unsigned short* Gt = Gp + (size_t)t * 64 * NG;
        unsigned short gi_u = Gt[0], gf_u = Gt[1024], gg_u = Gt[2048], go_u = Gt[3072];

        if (t > 0) {
            // per-wave wait: only this wave's 16 producers (one poll, parallel)
            while (!__all((int)(__hip_atomic_load(fwave, __ATOMIC_RELAXED, __HIP_MEMORY_SCOPE_AGENT) >= (unsigned)t)))
                __builtin_amdgcn_s_sleep(1);
            asm volatile("" ::: "memory");
        }

        // GEMM: gates[16 x 64] = h[16 x 1024] @ Wslice^T ; wave w owns K-slice
        // [w*256, (w+1)*256). Bulk-issue all 16 scoped 8B loads (MLP), then MFMAs.
        const size_t abase = (size_t)(t & 1) * 65536 + (size_t)bg * 16384;
        const unsigned long long* hp = (const unsigned long long*)(hread + abase)
                                       + ((size_t)w * 512 + lane) * 2;
        unsigned long long aq[16];
#pragma unroll
        for (int kk = 0; kk < 8; ++kk) {
            aq[kk * 2]     = __hip_atomic_load(hp + kk * 128,     __ATOMIC_RELAXED, __HIP_MEMORY_SCOPE_AGENT);
            aq[kk * 2 + 1] = __hip_atomic_load(hp + kk * 128 + 1, __ATOMIC_RELAXED, __HIP_MEMORY_SCOPE_AGENT);
        }
        floatx4 acc[4] = {};
#pragma unroll
        for (int kk = 0; kk < 8; ++kk) {
            union { unsigned long long q[2]; short8 v; } au;
            au.q[0] = aq[kk * 2]; au.q[1] = aq[kk * 2 + 1];
            const int cbase = ((w * 8 + kk) * 32 + kofs) ^ swz;
#pragma unroll
            for (int nt = 0; nt < 4; ++nt) {
                short8 bfr = *(const short8*)&w_lds[(nt * 16 + brow0) * 1024 + cbase];
                acc[nt] = __builtin_amdgcn_mfma_f32_16x16x32_bf16(au.v, bfr, acc[nt], 0, 0, 0);
            }
        }
        // D[m][n]: m = (lane>>4)*4 + r (batch), n = nt*16 + (lane&15) (gate row)
#pragma unroll
        for (int nt = 0; nt < 4; ++nt)
#pragma unroll
            for (int r = 0; r < 4; ++r)
                part[w][(lane >> 4) * 4 + r][nt * 16 + (lane & 15)] = acc[nt][r];
        __syncthreads();

        // reduce 4 wave-partials + LSTM cell for (b, u)
        float gi = (part[0][cb][nl]      + part[1][cb][nl])      + (part[2][cb][nl]      + part[3][cb][nl]);
        float gf = (part[0][cb][16 + nl] + part[1][cb][16 + nl]) + (part[2][cb][16 + nl] + part[3][cb][16 + nl]);
        float gg = (part[0][cb][32 + nl] + part[1][cb][32 + nl]) + (part[2][cb][32 + nl] + part[3][cb][32 + nl]);
        float go = (part[0][cb][48 + nl] + part[1][cb][48 + nl]) + (part[2][cb][48 + nl] + part[3][cb][48 + nl]);
        gi += bf2f(gi_u); gf += bf2f(gf_u); gg += bf2f(gg_u); go += bf2f(go_u);

        float c = fsigm(gf) * c_read + fsigm(gi) * ftanh(gg);
        float h = fsigm(go) * ftanh(c);

        // shift ring, compute interpolated read state for step t+1
        h3 = h2; h2 = h1; h1 = h0; h0 = h;
        c3 = c2; c2 = c1; c1 = c0; c0 = c;
        float hr = 0.3125f * h0 + 0.9375f * h1 - 0.3125f * h2 + 0.0625f * h3;
        c_read   = 0.3125f * c0 + 0.9375f * c1 - 0.3125f * c2 + 0.0625f * c3;

        // publish hr (bf16): pack 4 adjacent shorts via 2 shuffles -> one 8B
        // agent-scope write-through store per 4 threads
        {
            unsigned v  = (unsigned)f2bf(hr);
            unsigned p0 = v | (__shfl_xor(v, 1) << 16);     // valid at even nl
            unsigned p2 = __shfl_xor(p0, 2);                // partner pair
            if ((nl & 3) == 0) {
                unsigned long long q = (unsigned long long)p0 | ((unsigned long long)p2 << 32);
                unsigned long long* dst = (unsigned long long*)(hread
                    + (size_t)((t + 1) & 1) * 65536 + (size_t)bg * 16384 + pub_idx);
                __hip_atomic_store(dst, q, __ATOMIC_RELAXED, __HIP_MEMORY_SCOPE_AGENT);
            }
        }

        __syncthreads();  // drains vmcnt(0): publish stores of this block at LLC
        if (tid == 0)
            __hip_atomic_store(&flags[bg * 64 + rg], (unsigned)(t + 1), __ATOMIC_RELAXED, __HIP_MEMORY_SCOPE_AGENT);

        // HBM output stores AFTER the flag: their write-acks overlap the next
        // step instead of sitting inside the drain.
        out_h[(size_t)t * NH] = h;
        if (t == SEQT - 1) {
            float* o2 = out + (size_t)BATCH * SEQT * NH + (size_t)b * 2 * NH;
            o2[u] = h;
            o2[NH + u] = c;
        }
    }
}

// ---------------- host ----------------
extern "C" void kernel_launch(void* const* d_in, const int* in_sizes, int n_in,
                              void* d_out, int out_size, void* d_ws, size_t ws_size,
                              hipStream_t stream) {
    const float* x    = (const float*)d_in[0];
    const float* Wih  = (const float*)d_in[1];
    const float* Whh  = (const float*)d_in[2];
    const float* bih  = (const float*)d_in[3];
    const float* bhh  = (const float*)d_in[4];
    float* outp = (float*)d_out;

    char* ws = (char*)d_ws;
    unsigned short* xb    = (unsigned short*)(ws);                 // 33,554,432 B
    unsigned short* wihb  = (unsigned short*)(ws + 33554432);      //  4,194,304 B
    unsigned short* whhb  = (unsigned short*)(ws + 37748736);      //  8,388,608 B
    unsigned short* G     = (unsigned short*)(ws + 46137344);      // 268,435,456 B
    unsigned short* hread = (unsigned short*)(ws + 314572800);     //    262,144 B
    unsigned*       flags = (unsigned*)(ws + 314834944);           //      1,024 B

    // zero hread (step-0 state) and flags; visible to seq_kernel via dispatch boundary
    hipMemsetAsync(hread, 0, 262144 + 1024, stream);

    cvt_bf16<<<4096, 256, 0, stream>>>(x, xb, (long)BATCH * SEQT * NIN);
    cvt_bf16<<<2048, 256, 0, stream>>>(Wih, wihb, (long)NG * NIN);
    prep_whh<<<16384, 256, 0, stream>>>(Whh, whhb);
    gemm_ih<<<dim3(256, 32), 256, 0, stream>>>(xb, wihb, bih, bhh, G);

    void* args[] = { (void*)&whhb, (void*)&G, (void*)&hread, (void*)&flags, (void*)&outp };
    hipLaunchCooperativeKernel((void*)seq_kernel, dim3(256), dim3(256), args, 0, stream);
}